// Round 14
// baseline (75.069 us; speedup 1.0000x reference)
//
#include <hip/hip_runtime.h>

#define M_PAD 512

typedef float f32x4 __attribute__((ext_vector_type(4)));

// Seeded wave-parallel lower_bound over sorted ri[0..T): first idx with
// ri[idx] >= target. Seed window +-4096 around expected pos target*T/N
// (x8 gallop expansion keeps it provably correct), then 65-ary wave rounds.
__device__ __forceinline__ int lower_bound_seeded(const int* __restrict__ ri,
                                                  int T, int N, int target,
                                                  int lane) {
    int guess = (int)(((long long)target * T) / N);
    int W = 4096;
    int lo = max(0, guess - W), hi = min(T, guess + W);
    while (true) {
        bool okLo = (lo == 0) || (ri[lo - 1] < target);
        bool okHi = (hi == T) || (ri[hi] >= target);
        if (okLo && okHi) break;
        W <<= 3;
        lo = max(0, guess - W); hi = min(T, guess + W);
    }
    while (hi - lo > 64) {
        int len = hi - lo;
        int probe = lo + (len * (lane + 1)) / 65;
        int v = ri[probe];
        unsigned long long m = __ballot(v < target);
        int k = __popcll(m);
        int nlo = (k == 0)  ? lo : lo + (len * k) / 65;
        int nhi = (k == 64) ? hi : lo + (len * (k + 1)) / 65;
        lo = nlo; hi = nhi;
    }
    int p = lo + lane;
    int v = (p < hi) ? ri[p] : 2147483647;
    unsigned long long m = __ballot(v < target);
    return lo + __popcll(m);
}

// Single dispatch, block (1024 thr) covers rays r0, r0+1 (1024 slots).
// Search: waves 0..2 find the 3 boundaries. Then:
// Phase A (all threads, 1 slot each): xyz_out (valid) + xyz_w (all) nt-stores
//   - the two 16B/lane streams, unchanged from the 69us kernel.
// Phase B (threads 0..255, 4 slots each): reload ts/te (L1-hot from phase A),
//   recompute z/d, write z_vals/dists/ray_valid as DENSE f32x4 nt-stores ->
//   1KB/wave-instr runs per stream, 4x fewer stream switches (H3 test).
// No sync between A and B: B depends only on global inputs + sh[].
__global__ __launch_bounds__(1024)
void mono_kernel(const float* __restrict__ rays,
                 const int* __restrict__ ri,
                 const float* __restrict__ ts,
                 const float* __restrict__ te,
                 float* __restrict__ xyz_out,     // (T,4)
                 float* __restrict__ ray_valid,   // (N,512)
                 float* __restrict__ z_vals,      // (N,512)
                 float* __restrict__ dists,       // (N,512)
                 float* __restrict__ xyz_w,       // (N,512,4)
                 float* __restrict__ whole_valid, // (N,)
                 int N, int T) {
    const int r0 = blockIdx.x * 2;
    const int tid = threadIdx.x;
    const int wave = tid >> 6, lane = tid & 63;

    __shared__ int sh[3];
    if (wave < 3) {
        int lb = lower_bound_seeded(ri, T, N, r0 + wave, lane);
        if (lane == 0) sh[wave] = lb;
    }
    __syncthreads();

    // ---- Phase A: 16B/lane streams, 1 slot per thread ----
    {
        const int k = tid >> 9;              // local ray 0/1
        const int j = tid & (M_PAD - 1);
        const int r = r0 + k;
        const int s = sh[k];
        const int cnt = sh[k + 1] - s;

        f32x4 pt = {0.f, 0.f, 0.f, 0.f};
        if (j < cnt) {
            int i = s + j;
            float a = ts[i], bb = te[i];          // dense lane-consecutive
            float z = (a + bb) * 0.5f;
            const float* rc = rays + (size_t)r * 6;
            pt.x = fmaf(z, rc[3], rc[0]);
            pt.y = fmaf(z, rc[4], rc[1]);
            pt.z = fmaf(z, rc[5], rc[2]);
            __builtin_nontemporal_store(pt, reinterpret_cast<f32x4*>(xyz_out) + i);
        }
        __builtin_nontemporal_store(pt,
            reinterpret_cast<f32x4*>(xyz_w) + ((size_t)r << 9) + j);

        if (j == 0) whole_valid[r] = 1.0f;
    }

    // ---- Phase B: scalar streams as dense f32x4, threads 0..255 ----
    if (tid < 256) {
        const int q  = tid << 2;             // local slot base (0..1020)
        const int k  = q >> 9;               // local ray 0/1
        const int j0 = q & (M_PAD - 1);
        const int r  = r0 + k;
        const int s  = sh[k];
        const int cnt = sh[k + 1] - s;

        f32x4 z4 = {0.f, 0.f, 0.f, 0.f};
        f32x4 d4 = {0.f, 0.f, 0.f, 0.f};
        f32x4 v4 = {0.f, 0.f, 0.f, 0.f};
        #pragma unroll
        for (int e = 0; e < 4; ++e) {
            int j = j0 + e;
            if (j < cnt) {
                int i = s + j;
                float a = ts[i], bb = te[i];     // L1-hot (phase A touched them)
                z4[e] = (a + bb) * 0.5f;
                d4[e] = bb - a;
                v4[e] = 1.0f;
            }
        }
        size_t base4 = (((size_t)r << 9) + j0) >> 2;
        __builtin_nontemporal_store(z4, reinterpret_cast<f32x4*>(z_vals)    + base4);
        __builtin_nontemporal_store(d4, reinterpret_cast<f32x4*>(dists)     + base4);
        __builtin_nontemporal_store(v4, reinterpret_cast<f32x4*>(ray_valid) + base4);
    }
}

extern "C" void kernel_launch(void* const* d_in, const int* in_sizes, int n_in,
                              void* d_out, int out_size, void* d_ws, size_t ws_size,
                              hipStream_t stream) {
    const float* rays = (const float*)d_in[0];  // (N,6)
    const int*   ri   = (const int*)d_in[1];    // (T,) sorted
    const float* ts   = (const float*)d_in[2];  // (T,)
    const float* te   = (const float*)d_in[3];  // (T,)
    const int N = in_sizes[0] / 6;
    const int T = in_sizes[1];

    float* out         = (float*)d_out;
    float* xyz_out     = out;                                    // T*4
    float* ray_valid   = xyz_out + (size_t)T * 4;                // N*512
    float* z_vals      = ray_valid + (size_t)N * M_PAD;          // N*512
    float* dists       = z_vals + (size_t)N * M_PAD;             // N*512
    float* whole_valid = dists + (size_t)N * M_PAD;              // N
    float* xyz_w       = whole_valid + N;                        // N*512*4

    mono_kernel<<<N / 2, 1024, 0, stream>>>(rays, ri, ts, te,
                                            xyz_out, ray_valid, z_vals,
                                            dists, xyz_w, whole_valid, N, T);
}